// Round 1
// baseline (176.242 us; speedup 1.0000x reference)
//
#include <hip/hip_runtime.h>
#include <math.h>

#define DDIM 200
#define CCH 50
#define NT 256

// One block per batch element.
// Phase 1: threads 0..199 load src/rel/tail embedding vectors to LDS.
// Phase 2: thread e computes src_e[e], tail_e[e] = sum_d v[d]*W[r][d][e]
//          (single coalesced pass over W, 2 FMA per 4B), then tanh.
// Phase 3: block-strided fused conv+relu+fc dot, block reduction -> out[b].
__global__ __launch_bounds__(NT) void spkbgat_fused_kernel(
    const int*   __restrict__ batch_inputs,  // (B,3) int32
    const float* __restrict__ ent,           // (100000, 200)
    const float* __restrict__ rel_emb,       // (237, 200)
    const float* __restrict__ W,             // (237, 200, 200)
    const float* __restrict__ conv_w,        // (50, 3)
    const float* __restrict__ conv_b,        // (50,)
    const float* __restrict__ fc_w,          // (10000,)
    const float* __restrict__ fc_b,          // (1,)
    float*       __restrict__ out)           // (B,)
{
    __shared__ float s_sh[DDIM];
    __shared__ float r_sh[DDIM];
    __shared__ float t_sh[DDIM];
    __shared__ float se_sh[DDIM];
    __shared__ float te_sh[DDIM];
    __shared__ float red[NT / 64];

    const int b   = blockIdx.x;
    const int tid = threadIdx.x;

    const int h = batch_inputs[b * 3 + 0];
    const int r = batch_inputs[b * 3 + 1];
    const int t = batch_inputs[b * 3 + 2];

    if (tid < DDIM) {
        s_sh[tid] = ent[(long)h * DDIM + tid];
        r_sh[tid] = rel_emb[r * DDIM + tid];
        t_sh[tid] = ent[(long)t * DDIM + tid];
    }
    __syncthreads();

    // Phase 2: dual matvec over one coalesced W pass.
    const float* __restrict__ Wr = W + (long)r * DDIM * DDIM;
    if (tid < DDIM) {
        float acc_s = 0.f;
        float acc_t = 0.f;
        #pragma unroll 8
        for (int d = 0; d < DDIM; ++d) {
            const float w = Wr[d * DDIM + tid];   // lanes read contiguous 800B row
            acc_s = fmaf(s_sh[d], w, acc_s);
            acc_t = fmaf(t_sh[d], w, acc_t);
        }
        se_sh[tid] = tanhf(acc_s);
        te_sh[tid] = tanhf(acc_t);
    }
    __syncthreads();

    // Phase 3: out[b] = sum_{c,d} relu(cw0[c]*se[d]+cw1[c]*rl[d]+cw2[c]*te[d]+cb[c]) * fcw[c*200+d]
    float sum = 0.f;
    for (int idx = tid; idx < CCH * DDIM; idx += NT) {
        const int c = idx / DDIM;
        const int d = idx - c * DDIM;
        float v = conv_w[c * 3 + 0] * se_sh[d]
                + conv_w[c * 3 + 1] * r_sh[d]
                + conv_w[c * 3 + 2] * te_sh[d]
                + conv_b[c];
        v = fmaxf(v, 0.f);
        sum = fmaf(v, fc_w[idx], sum);
    }

    // wave64 butterfly + cross-wave LDS reduce
    #pragma unroll
    for (int off = 32; off > 0; off >>= 1)
        sum += __shfl_down(sum, off, 64);
    if ((tid & 63) == 0) red[tid >> 6] = sum;
    __syncthreads();
    if (tid == 0) {
        out[b] = red[0] + red[1] + red[2] + red[3] + fc_b[0];
    }
}

extern "C" void kernel_launch(void* const* d_in, const int* in_sizes, int n_in,
                              void* d_out, int out_size, void* d_ws, size_t ws_size,
                              hipStream_t stream) {
    const int*   batch_inputs = (const int*)  d_in[0];
    const float* ent          = (const float*)d_in[1];
    const float* rel_emb      = (const float*)d_in[2];
    const float* W            = (const float*)d_in[3];
    const float* conv_w       = (const float*)d_in[4];
    const float* conv_b       = (const float*)d_in[5];
    const float* fc_w         = (const float*)d_in[6];
    const float* fc_b         = (const float*)d_in[7];
    float*       out          = (float*)d_out;

    const int B = in_sizes[0] / 3;  // 8192

    spkbgat_fused_kernel<<<B, NT, 0, stream>>>(
        batch_inputs, ent, rel_emb, W, conv_w, conv_b, fc_w, fc_b, out);
}

// Round 2
// 83.315 us; speedup vs baseline: 2.1154x; 2.1154x over previous
//
#include <hip/hip_runtime.h>
#include <math.h>

#define DDIM 200
#define CCH  50
#define NREL 237
#define NT   256
#define EPB  4   // elements per block (one per wave)

// ---------- Kernel 1: counting sort by relation -> perm[] in d_ws ----------
__global__ __launch_bounds__(1024) void relsort_kernel(
    const int* __restrict__ bi, int B, int* __restrict__ perm)
{
    __shared__ int hist[NREL];
    __shared__ int offs[NREL];
    const int tid = threadIdx.x;
    for (int i = tid; i < NREL; i += 1024) hist[i] = 0;
    __syncthreads();
    for (int i = tid; i < B; i += 1024)
        atomicAdd(&hist[bi[i * 3 + 1]], 1);
    __syncthreads();
    if (tid == 0) {
        int acc = 0;
        for (int r = 0; r < NREL; ++r) { offs[r] = acc; acc += hist[r]; }
    }
    __syncthreads();
    for (int i = tid; i < B; i += 1024) {
        int pos = atomicAdd(&offs[bi[i * 3 + 1]], 1);
        perm[pos] = i;
    }
}

// ---------- Kernel 2: fused matvec+tanh+conv+fc, one wave per element ----------
__global__ __launch_bounds__(NT, 8) void spkbgat_main_kernel(
    const int*   __restrict__ bi,
    const float* __restrict__ ent,
    const float* __restrict__ rel_emb,
    const float* __restrict__ W,
    const float* __restrict__ conv_w,
    const float* __restrict__ conv_b,
    const float* __restrict__ fc_w,
    const float* __restrict__ fc_b,
    const int*   __restrict__ perm,
    int B, int nwg,
    float*       __restrict__ out)
{
    __shared__ float st_sh[EPB][DDIM][2];   // {src,tail} interleaved; reused for {se,te}
    __shared__ float rl_sh[EPB][DDIM];
    __shared__ float cwb[CCH][4];           // {w0,w1,w2,b}

    const int tid  = threadIdx.x;
    const int w    = tid >> 6;
    const int lane = tid & 63;

    // stage conv weights (block-wide)
    if (tid < CCH) {
        cwb[tid][0] = conv_w[tid * 3 + 0];
        cwb[tid][1] = conv_w[tid * 3 + 1];
        cwb[tid][2] = conv_w[tid * 3 + 2];
        cwb[tid][3] = conv_b[tid];
    }

    // bijective XCD swizzle (m204): XCD x processes a contiguous sorted chunk
    const int bid = blockIdx.x;
    const int q   = nwg >> 3, rmd = nwg & 7;
    const int xcd = bid & 7,  idx = bid >> 3;
    const int swz = (xcd < rmd ? xcd * (q + 1) : rmd * (q + 1) + (xcd - rmd) * q) + idx;
    const int spos  = swz * EPB + w;
    const bool valid = (spos < B);

    __syncthreads();   // cwb visible to all waves (single barrier, all threads reach it)
    if (!valid) return;

    const int b = perm[spos];
    const int h = bi[b * 3 + 0];
    const int r = bi[b * 3 + 1];
    const int t = bi[b * 3 + 2];

    // per-wave staging of src/tail (interleaved) and rel
    {
        const float* __restrict__ sp = ent + (long)h * DDIM;
        const float* __restrict__ tp = ent + (long)t * DDIM;
        const float* __restrict__ rp = rel_emb + r * DDIM;
        for (int d = lane; d < DDIM; d += 64) {
            st_sh[w][d][0] = sp[d];
            st_sh[w][d][1] = tp[d];
            rl_sh[w][d]    = rp[d];
        }
    }

    // dual matvec: lane c (<50) owns cols 4c..4c+3; coalesced float4 W rows
    if (lane < CCH) {
        const float4* __restrict__ wp =
            (const float4*)(W + (size_t)r * (DDIM * DDIM)) + lane;
        float4 as = {0.f, 0.f, 0.f, 0.f};
        float4 at = {0.f, 0.f, 0.f, 0.f};
        #pragma unroll 4
        for (int d = 0; d < DDIM; ++d) {
            const float4 wv = wp[d * (DDIM / 4)];
            const float2 st = *(const float2*)&st_sh[w][d][0];
            as.x = fmaf(st.x, wv.x, as.x);
            as.y = fmaf(st.x, wv.y, as.y);
            as.z = fmaf(st.x, wv.z, as.z);
            as.w = fmaf(st.x, wv.w, as.w);
            at.x = fmaf(st.y, wv.x, at.x);
            at.y = fmaf(st.y, wv.y, at.y);
            at.z = fmaf(st.y, wv.z, at.z);
            at.w = fmaf(st.y, wv.w, at.w);
        }
        const float4 se = {tanhf(as.x), tanhf(as.y), tanhf(as.z), tanhf(as.w)};
        const float4 te = {tanhf(at.x), tanhf(at.y), tanhf(at.z), tanhf(at.w)};
        // overwrite st_sh with {se,te} interleaved (same-wave RAW handled by lgkmcnt)
        const float4 p0 = {se.x, te.x, se.y, te.y};
        const float4 p1 = {se.z, te.z, se.w, te.w};
        *(float4*)&st_sh[w][4 * lane][0]     = p0;
        *(float4*)&st_sh[w][4 * lane + 2][0] = p1;
    }

    // fused conv+relu+fc: 50c x 50(d/4) tasks over the wave
    float sum = 0.f;
    for (int task = lane; task < CCH * (DDIM / 4); task += 64) {
        const int c  = task / (DDIM / 4);
        const int d  = (task - c * (DDIM / 4)) * 4;
        const float4 q0 = *(const float4*)&st_sh[w][d][0];      // se0,te0,se1,te1
        const float4 q1 = *(const float4*)&st_sh[w][d + 2][0];  // se2,te2,se3,te3
        const float4 rv = *(const float4*)&rl_sh[w][d];
        const float4 cw = *(const float4*)&cwb[c][0];
        const float4 fv = *(const float4*)&fc_w[c * DDIM + d];
        const float v0 = fmaf(cw.x, q0.x, fmaf(cw.y, rv.x, fmaf(cw.z, q0.y, cw.w)));
        const float v1 = fmaf(cw.x, q0.z, fmaf(cw.y, rv.y, fmaf(cw.z, q0.w, cw.w)));
        const float v2 = fmaf(cw.x, q1.x, fmaf(cw.y, rv.z, fmaf(cw.z, q1.y, cw.w)));
        const float v3 = fmaf(cw.x, q1.z, fmaf(cw.y, rv.w, fmaf(cw.z, q1.w, cw.w)));
        sum = fmaf(fmaxf(v0, 0.f), fv.x, sum);
        sum = fmaf(fmaxf(v1, 0.f), fv.y, sum);
        sum = fmaf(fmaxf(v2, 0.f), fv.z, sum);
        sum = fmaf(fmaxf(v3, 0.f), fv.w, sum);
    }

    // wave64 butterfly
    #pragma unroll
    for (int off = 32; off; off >>= 1)
        sum += __shfl_down(sum, off, 64);
    if (lane == 0) out[b] = sum + fc_b[0];
}

extern "C" void kernel_launch(void* const* d_in, const int* in_sizes, int n_in,
                              void* d_out, int out_size, void* d_ws, size_t ws_size,
                              hipStream_t stream) {
    const int*   bi      = (const int*)  d_in[0];
    const float* ent     = (const float*)d_in[1];
    const float* rel_emb = (const float*)d_in[2];
    const float* W       = (const float*)d_in[3];
    const float* conv_w  = (const float*)d_in[4];
    const float* conv_b  = (const float*)d_in[5];
    const float* fc_w    = (const float*)d_in[6];
    const float* fc_b    = (const float*)d_in[7];
    float*       out     = (float*)d_out;

    const int B   = in_sizes[0] / 3;            // 8192
    int*      perm = (int*)d_ws;
    const int nwg = (B + EPB - 1) / EPB;        // 2048

    relsort_kernel<<<1, 1024, 0, stream>>>(bi, B, perm);
    spkbgat_main_kernel<<<nwg, NT, 0, stream>>>(
        bi, ent, rel_emb, W, conv_w, conv_b, fc_w, fc_b, perm, B, nwg, out);
}